// Round 12
// baseline (74.931 us; speedup 1.0000x reference)
//
#include <hip/hip_runtime.h>
#include <hip/hip_fp16.h>

#define NS 512
#define NR 32768
#define NB 1024
#define Q 16                 // r-splits (sixteenths)
#define NQ (NR / Q)          // 2048 reactions per split
#define G 8                  // batches per block
#define NG (NB / G)          // 128 batch groups
#define ELLK 64              // slots per (split, species); negs grow up, pos grow down

typedef unsigned short u16x4 __attribute__((ext_vector_type(4)));

// ws layout (bytes):
//   pA   float4[NR]          @ 0       (524288)  alpha,beta,gamma,cr_coef
//   pB   float2[NR]          @ 524288  (262144)  fuv_coef, (s1|s2<<16) bits
//   cntN int[Q*NS]           @ 786432  (32768)
//   cntP int[Q*NS]           @ 819200  (32768)
//   perm uint[Q*NS]          @ 851968  (32768)   rank -> (s | nn<<16 | np<<24)
//   ell  u16[Q][NS][ELLK]    @ 884736  (1048576) negs at [0,nn), pos at [64-np,64)
// total 1,933,312 B

static __device__ __forceinline__ float rfl(float v) {
  return __int_as_float(__builtin_amdgcn_readfirstlane(__float_as_int(v)));
}
static __device__ __forceinline__ unsigned int pkrtz(float a, float b) {
  auto h = __builtin_amdgcn_cvt_pkrtz(a, b);
  return *reinterpret_cast<unsigned int*>(&h);
}
static __device__ __forceinline__ __half2 bch2(unsigned int w) {
  return *reinterpret_cast<__half2*>(&w);
}
static __device__ __forceinline__ unsigned int h2u(__half2 h) {
  return *reinterpret_cast<unsigned int*>(&h);
}

// Merged prep + find_pr + out-zeroing. Grid 1024 = 32 r-blocks x 32 s-blocks.
__global__ __launch_bounds__(256) void build(
    const float* __restrict__ inc, const int* __restrict__ msi,
    const float* __restrict__ alpha, const float* __restrict__ beta,
    const float* __restrict__ gam,   const float* __restrict__ crc,
    const float* __restrict__ fvc,
    float4* __restrict__ pA, float2* __restrict__ pB,
    int* __restrict__ cntN, int* __restrict__ cntP,
    unsigned short* __restrict__ ell, float* __restrict__ out) {
  int rblk = blockIdx.x & 31;
  int sblk = blockIdx.x >> 5;
  int t = threadIdx.x;
  int rbase = rblk * 1024 + 4 * t;

  // ---- pr scan over 16 s-rows ----
  int4 a = reinterpret_cast<const int4*>(msi)[rbase >> 1];
  int4 b = reinterpret_cast<const int4*>(msi)[(rbase >> 1) + 1];
  int s1v[4] = {a.x, a.z, b.x, b.z};
  int s2v[4] = {a.y, a.w, b.y, b.w};
  int pr[4] = {-1, -1, -1, -1};
  int s0 = sblk * 16;
#pragma unroll
  for (int ss = 0; ss < 16; ++ss) {
    int s = s0 + ss;
    float4 v = reinterpret_cast<const float4*>(inc)[((size_t)s * NR + rbase) >> 2];
    float vv[4] = {v.x, v.y, v.z, v.w};
#pragma unroll
    for (int j = 0; j < 4; ++j) {
      float c = vv[j] + (float)(s == s1v[j]) + (float)(s == s2v[j]);
      if (c > 0.5f) pr[j] = s;
    }
  }
#pragma unroll
  for (int j = 0; j < 4; ++j) {
    if (pr[j] >= 0) {
      int r = rbase + j;
      int cell = (r >> 11) * NS + pr[j];
      int p = atomicAdd(&cntP[cell], 1);
      if (p < ELLK)
        ell[(cell << 6) + 63 - p] = (unsigned short)(r & (NQ - 1));
    }
  }

  // ---- pack duties: 32 reactions per block ----
  if (t < 32) {
    int r = rblk * 1024 + sblk * 32 + t;
    pA[r] = make_float4(alpha[r], beta[r], gam[r], crc[r]);
    int s1 = msi[2 * r], s2 = msi[2 * r + 1];
    pB[r] = make_float2(fvc[r], __int_as_float(s1 | (s2 << 16)));
    int e16 = r >> 11;
    unsigned short idx = (unsigned short)(r & (NQ - 1));
    int c1 = e16 * NS + s1;
    int p1 = atomicAdd(&cntN[c1], 1);
    if (p1 < ELLK) ell[(c1 << 6) + p1] = idx;
    int c2 = e16 * NS + s2;
    int p2 = atomicAdd(&cntN[c2], 1);
    if (p2 < ELLK) ell[(c2 << 6) + p2] = idx;
  }

  // ---- zero d_out slice: 128 float4 per block x 1024 blocks = 2 MB ----
  if (t < 128) {
    reinterpret_cast<float4*>(out)[blockIdx.x * 128 + t] =
        make_float4(0.f, 0.f, 0.f, 0.f);
  }
}

// Per-split descending count-sort of species -> perm[rank] = s | nn<<16 | np<<24.
__global__ __launch_bounds__(512) void balance(
    const int* __restrict__ cntN, const int* __restrict__ cntP,
    unsigned int* __restrict__ perm) {
  __shared__ unsigned short c[NS];
  int e16 = blockIdx.x;
  int t = threadIdx.x;
  int nn = cntN[e16 * NS + t]; nn = nn < ELLK ? nn : ELLK;
  int np = cntP[e16 * NS + t]; np = np < ELLK ? np : ELLK;
  int my = nn + np;
  c[t] = (unsigned short)my;
  __syncthreads();
  int rank = 0;
#pragma unroll 8
  for (int s = 0; s < NS; ++s) {
    int cs = c[s];
    rank += (cs > my) || (cs == my && s < t);
  }
  perm[e16 * NS + rank] =
      (unsigned int)t | ((unsigned int)nn << 16) | ((unsigned int)np << 24);
}

// One block per (batch-group, split-PAIR). 512 threads, 40 KB LDS -> 4 blocks/CU.
__global__ __launch_bounds__(512, 8) void fused(
    const float* __restrict__ ab, const float* __restrict__ temp,
    const float* __restrict__ crr, const float* __restrict__ fvr,
    const float4* __restrict__ pA, const float2* __restrict__ pB,
    const unsigned int* __restrict__ perm, const unsigned short* __restrict__ ell,
    float* __restrict__ out) {
  __shared__ uint4 gL[NQ];            // 32 KB: 4x half2 = 8 batches per reaction
  __shared__ uint4 abH[NS];           // 8 KB: 4x half2 ab per species (8 batches)
  int t = threadIdx.x;
  int grp = blockIdx.x & (NG - 1);
  int ep = blockIdx.x >> 7;           // 0..Q/2-1 -> splits {2ep, 2ep+1}

  float av[G];
#pragma unroll
  for (int i = 0; i < G; ++i) av[i] = ab[(size_t)(grp + i * NG) * NS + t];
  abH[t] = make_uint4(h2u(__floats2half2_rn(av[0], av[1])),
                      h2u(__floats2half2_rn(av[2], av[3])),
                      h2u(__floats2half2_rn(av[4], av[5])),
                      h2u(__floats2half2_rn(av[6], av[7])));

  float lt[G], mg[G], cb[G], fb[G];
#pragma unroll
  for (int i = 0; i < G; ++i) {
    int b = grp + i * NG;
    float T = rfl(temp[b]);
    lt[i] = rfl(log2f(T * (1.0f / 300.0f)));
    mg[i] = rfl(-1.4426950408889634f / T);
    cb[i] = rfl(crr[b]);
    fb[i] = rfl(fvr[b]);
  }

  int spv[2];
  float o[2][G];

#pragma unroll
  for (int half = 0; half < 2; ++half) {
    int e16 = ep * 2 + half;
    int rbase = e16 * NQ;
    unsigned int pc = perm[e16 * NS + t];
    __syncthreads();   // abH ready (half 0) / prior phase-2 gL reads done (half 1)

    // ---- phase 1: rates (f32) -> pack -> f16 multiply by factors ----
#pragma unroll
    for (int it = 0; it < NQ / 512; ++it) {
      int rl = t + 512 * it;
      float4 a4 = pA[rbase + rl];
      float2 bb = pB[rbase + rl];
      int idx = __float_as_int(bb.y);
      uint4 u = abH[idx & 0xffff];
      uint4 v = abH[idx >> 16];
      float r[G];
#pragma unroll
      for (int i = 0; i < G; ++i) {
        float e = __builtin_amdgcn_exp2f(fmaf(a4.y, lt[i], a4.z * mg[i]));
        r[i] = fmaf(a4.x, e, fmaf(a4.w, cb[i], bb.x * fb[i]));
      }
      unsigned int w01 = h2u(__hmul2(bch2(pkrtz(r[0], r[1])),
                                     __hmul2(bch2(u.x), bch2(v.x))));
      unsigned int w23 = h2u(__hmul2(bch2(pkrtz(r[2], r[3])),
                                     __hmul2(bch2(u.y), bch2(v.y))));
      unsigned int w45 = h2u(__hmul2(bch2(pkrtz(r[4], r[5])),
                                     __hmul2(bch2(u.z), bch2(v.z))));
      unsigned int w67 = h2u(__hmul2(bch2(pkrtz(r[6], r[7])),
                                     __hmul2(bch2(u.w), bch2(v.w))));
      gL[rl] = make_uint4(w01, w23, w45, w67);
    }
    __syncthreads();

    // ---- phase 2: two sign-clean gather loops (negs up, pos down) ----
    int sp = pc & 0xffff;
    int nn = (pc >> 16) & 0xff;
    int np = (pc >> 24) & 0xff;
    const unsigned short* row = ell + ((size_t)(ep * 2 + half) * NS + sp) * ELLK;

    __half2 N01 = bch2(0u), N23 = bch2(0u), N45 = bch2(0u), N67 = bch2(0u);
    __half2 P01 = bch2(0u), P23 = bch2(0u), P45 = bch2(0u), P67 = bch2(0u);

    int nf = nn >> 2;
    for (int k = 0; k < nf; ++k) {
      u16x4 cur = *reinterpret_cast<const u16x4*>(row + 4 * k);
      uint4 g0 = gL[cur[0] & (NQ - 1)];
      uint4 g1 = gL[cur[1] & (NQ - 1)];
      uint4 g2 = gL[cur[2] & (NQ - 1)];
      uint4 g3 = gL[cur[3] & (NQ - 1)];
      N01 = __hadd2(N01, __hadd2(__hadd2(bch2(g0.x), bch2(g1.x)),
                                 __hadd2(bch2(g2.x), bch2(g3.x))));
      N23 = __hadd2(N23, __hadd2(__hadd2(bch2(g0.y), bch2(g1.y)),
                                 __hadd2(bch2(g2.y), bch2(g3.y))));
      N45 = __hadd2(N45, __hadd2(__hadd2(bch2(g0.z), bch2(g1.z)),
                                 __hadd2(bch2(g2.z), bch2(g3.z))));
      N67 = __hadd2(N67, __hadd2(__hadd2(bch2(g0.w), bch2(g1.w)),
                                 __hadd2(bch2(g2.w), bch2(g3.w))));
    }
    if (nn & 3) {
      u16x4 cur = *reinterpret_cast<const u16x4*>(row + 4 * nf);
#pragma unroll
      for (int j = 0; j < 4; ++j) {
        bool valid = (4 * nf + j) < nn;
        uint4 g = gL[cur[j] & (NQ - 1)];
        __half2 cf = bch2(valid ? 0x3C003C00u : 0u);
        N01 = __hfma2(bch2(g.x), cf, N01);
        N23 = __hfma2(bch2(g.y), cf, N23);
        N45 = __hfma2(bch2(g.z), cf, N45);
        N67 = __hfma2(bch2(g.w), cf, N67);
      }
    }

    int pf = np >> 2;
    for (int k = 0; k < pf; ++k) {
      u16x4 cur = *reinterpret_cast<const u16x4*>(row + 60 - 4 * k);
      uint4 g0 = gL[cur[0] & (NQ - 1)];
      uint4 g1 = gL[cur[1] & (NQ - 1)];
      uint4 g2 = gL[cur[2] & (NQ - 1)];
      uint4 g3 = gL[cur[3] & (NQ - 1)];
      P01 = __hadd2(P01, __hadd2(__hadd2(bch2(g0.x), bch2(g1.x)),
                                 __hadd2(bch2(g2.x), bch2(g3.x))));
      P23 = __hadd2(P23, __hadd2(__hadd2(bch2(g0.y), bch2(g1.y)),
                                 __hadd2(bch2(g2.y), bch2(g3.y))));
      P45 = __hadd2(P45, __hadd2(__hadd2(bch2(g0.z), bch2(g1.z)),
                                 __hadd2(bch2(g2.z), bch2(g3.z))));
      P67 = __hadd2(P67, __hadd2(__hadd2(bch2(g0.w), bch2(g1.w)),
                                 __hadd2(bch2(g2.w), bch2(g3.w))));
    }
    if (np & 3) {
      int base = 60 - 4 * pf;
      u16x4 cur = *reinterpret_cast<const u16x4*>(row + base);
#pragma unroll
      for (int j = 0; j < 4; ++j) {
        bool valid = (base + j) >= (64 - np);
        uint4 g = gL[cur[j] & (NQ - 1)];
        __half2 cf = bch2(valid ? 0x3C003C00u : 0u);
        P01 = __hfma2(bch2(g.x), cf, P01);
        P23 = __hfma2(bch2(g.y), cf, P23);
        P45 = __hfma2(bch2(g.z), cf, P45);
        P67 = __hfma2(bch2(g.w), cf, P67);
      }
    }

    spv[half] = sp;
    float2 p01 = __half22float2(P01), n01 = __half22float2(N01);
    float2 p23 = __half22float2(P23), n23 = __half22float2(N23);
    float2 p45 = __half22float2(P45), n45 = __half22float2(N45);
    float2 p67 = __half22float2(P67), n67 = __half22float2(N67);
    o[half][0] = p01.x - n01.x; o[half][1] = p01.y - n01.y;
    o[half][2] = p23.x - n23.x; o[half][3] = p23.y - n23.y;
    o[half][4] = p45.x - n45.x; o[half][5] = p45.y - n45.y;
    o[half][6] = p67.x - n67.x; o[half][7] = p67.y - n67.y;
  }

  // ---- de-permute both halves via float4 staging overlaid on dead gL ----
  __syncthreads();
  float4* stg = reinterpret_cast<float4*>(gL);   // [NS][2] float4
  stg[spv[0] * 2 + 0] = make_float4(o[0][0], o[0][1], o[0][2], o[0][3]);
  stg[spv[0] * 2 + 1] = make_float4(o[0][4], o[0][5], o[0][6], o[0][7]);
  __syncthreads();
  float4 q0 = stg[spv[1] * 2 + 0];
  float4 q1 = stg[spv[1] * 2 + 1];
  q0.x += o[1][0]; q0.y += o[1][1]; q0.z += o[1][2]; q0.w += o[1][3];
  q1.x += o[1][4]; q1.y += o[1][5]; q1.z += o[1][6]; q1.w += o[1][7];
  stg[spv[1] * 2 + 0] = q0;
  stg[spv[1] * 2 + 1] = q1;
  __syncthreads();
  float4 r0 = stg[t * 2 + 0];
  float4 r1 = stg[t * 2 + 1];
  unsafeAtomicAdd(&out[(size_t)(grp + 0 * NG) * NS + t], r0.x);
  unsafeAtomicAdd(&out[(size_t)(grp + 1 * NG) * NS + t], r0.y);
  unsafeAtomicAdd(&out[(size_t)(grp + 2 * NG) * NS + t], r0.z);
  unsafeAtomicAdd(&out[(size_t)(grp + 3 * NG) * NS + t], r0.w);
  unsafeAtomicAdd(&out[(size_t)(grp + 4 * NG) * NS + t], r1.x);
  unsafeAtomicAdd(&out[(size_t)(grp + 5 * NG) * NS + t], r1.y);
  unsafeAtomicAdd(&out[(size_t)(grp + 6 * NG) * NS + t], r1.z);
  unsafeAtomicAdd(&out[(size_t)(grp + 7 * NG) * NS + t], r1.w);
}

extern "C" void kernel_launch(void* const* d_in, const int* in_sizes, int n_in,
                              void* d_out, int out_size, void* d_ws, size_t ws_size,
                              hipStream_t stream) {
  const float* ab    = (const float*)d_in[1];
  const float* temp  = (const float*)d_in[2];
  const float* crr   = (const float*)d_in[3];
  const float* fvr   = (const float*)d_in[4];
  const float* inc   = (const float*)d_in[5];
  const float* alpha = (const float*)d_in[6];
  const float* beta  = (const float*)d_in[7];
  const float* gam   = (const float*)d_in[8];
  const float* crc   = (const float*)d_in[9];
  const float* fvc   = (const float*)d_in[10];
  const int*   msi   = (const int*)d_in[12];

  char* ws = (char*)d_ws;
  float4* pA           = (float4*)(ws);
  float2* pB           = (float2*)(ws + 524288);
  int* cntN            = (int*)(ws + 786432);
  int* cntP            = (int*)(ws + 819200);
  unsigned int* perm   = (unsigned int*)(ws + 851968);
  unsigned short* ellp = (unsigned short*)(ws + 884736);
  float* out = (float*)d_out;

  hipMemsetAsync(cntN, 0, 2 * Q * NS * sizeof(int), stream);   // cntN + cntP
  build<<<1024, 256, 0, stream>>>(inc, msi, alpha, beta, gam, crc, fvc,
                                  pA, pB, cntN, cntP, ellp, out);
  balance<<<Q, 512, 0, stream>>>(cntN, cntP, perm);
  fused<<<NG * Q / 2, 512, 0, stream>>>(ab, temp, crr, fvr, pA, pB, perm, ellp, out);
}